// Round 5
// baseline (62.256 us; speedup 1.0000x reference)
//
#include <hip/hip_runtime.h>

// Per-channel histogram: in [LENGTH=1e6, C=64] int32 values in [0,256),
// out [64, 256] int32 counts. Memory-bound: 256 MB read -> ~41 us floor.
//
// R5: (1) dense loads - one int4 per lane (64 lanes x 16 B = 1 KB contiguous
// per instruction; previous scheme had 16 B holes -> 2x TA request rate).
// int4 index m covers channels (m&15)*4..+3; stride % 16 == 0 keeps the
// channel base per-thread invariant. (2) 2 blocks/CU (512 blocks, 128 KB
// LDS/CU, launch_bounds(1024,8) -> <=64 VGPR, 32 waves/CU) to keep the HBM
// queue full while waves run their VALU+LDS-atomic bursts. Body kept lean
// (<=2 int4 live) so the 64-VGPR cap cannot spill (R3's mistake).

#define NCH   64
#define NBINS 256
#define HIST_SIZE (NCH * NBINS)   // 16384 ints = 64 KB LDS
#define NQWORDS   (HIST_SIZE / 2) // 8192 packed pairs
#define THREADS 1024
#define BLOCKS  512               // 2 blocks/CU

__global__ __launch_bounds__(THREADS, 8) void hist_kernel(
    const int* __restrict__ in, unsigned long long* __restrict__ out, long long n4)
{
    __shared__ int hist[HIST_SIZE];
    const int tid = threadIdx.x;

    #pragma unroll
    for (int k = 0; k < HIST_SIZE / THREADS; ++k)
        hist[tid + k * THREADS] = 0;
    __syncthreads();

    const int4* __restrict__ in4 = (const int4*)in;
    const long long stride = (long long)BLOCKS * THREADS;      // divisible by 16
    const long long gid = (long long)blockIdx.x * THREADS + tid;

    // int4 m covers flat ints [4m,4m+4) -> channels (m&15)*4..+3.
    const int c0 = (int)((gid & 15) << 2);
    int* __restrict__ h = &hist[c0 * NBINS];

    // Uniform trip count: threads gid < rem do one extra int4 at the end.
    const long long full = n4 / stride;
    const long long rem  = n4 - full * stride;

    long long i = gid;
    long long k = 0;
    for (; k + 2 <= full; k += 2, i += 2 * stride) {
        int4 a = in4[i];
        int4 b = in4[i + stride];
        atomicAdd(&h[0 * NBINS + a.x], 1); atomicAdd(&h[1 * NBINS + a.y], 1);
        atomicAdd(&h[2 * NBINS + a.z], 1); atomicAdd(&h[3 * NBINS + a.w], 1);
        atomicAdd(&h[0 * NBINS + b.x], 1); atomicAdd(&h[1 * NBINS + b.y], 1);
        atomicAdd(&h[2 * NBINS + b.z], 1); atomicAdd(&h[3 * NBINS + b.w], 1);
    }
    if (k < full) {
        int4 a = in4[i];
        atomicAdd(&h[0 * NBINS + a.x], 1); atomicAdd(&h[1 * NBINS + a.y], 1);
        atomicAdd(&h[2 * NBINS + a.z], 1); atomicAdd(&h[3 * NBINS + a.w], 1);
        i += stride;
    }
    if (gid < rem) {
        int4 a = in4[i];
        atomicAdd(&h[0 * NBINS + a.x], 1); atomicAdd(&h[1 * NBINS + a.y], 1);
        atomicAdd(&h[2 * NBINS + a.z], 1); atomicAdd(&h[3 * NBINS + a.w], 1);
    }
    __syncthreads();

    // Flush block-private histogram as packed 64-bit adds (two bins/atomic).
    // Per-bin totals << 2^32 -> no carry across halves. Rotate start offset
    // per block to spread L2 line contention. (R2 showed atomic count here
    // is not a limiter.)
    const unsigned long long* __restrict__ h64 = (const unsigned long long*)hist;
    #pragma unroll
    for (int kk = 0; kk < NQWORDS / THREADS; ++kk) {
        const int j = (tid + kk * THREADS + blockIdx.x * 32) & (NQWORDS - 1);
        const unsigned long long v = h64[j];
        if (v) atomicAdd(&out[j], v);
    }
}

extern "C" void kernel_launch(void* const* d_in, const int* in_sizes, int n_in,
                              void* d_out, int out_size, void* d_ws, size_t ws_size,
                              hipStream_t stream) {
    const int* in = (const int*)d_in[0];
    unsigned long long* out = (unsigned long long*)d_out;
    const long long n = (long long)in_sizes[0];   // 64,000,000 (divisible by 4)
    const long long n4 = n / 4;

    // Replays accumulate via atomics -> must zero the output every launch.
    hipMemsetAsync(d_out, 0, (size_t)out_size * sizeof(int), stream);

    hist_kernel<<<BLOCKS, THREADS, 0, stream>>>(in, out, n4);
}

// Round 6
// 53.677 us; speedup vs baseline: 1.1598x; 1.1598x over previous
//
#include <hip/hip_runtime.h>

// Per-channel histogram: in [LENGTH=1e6, C=64] int32 values in [0,256),
// out [64, 256] int32 counts. Memory-bound: 256 MB read.
//
// R6: contiguous block segments instead of grid-stride. Each block owns a
// 1 MB contiguous slice (62500 int4); per iteration it reads 16 KB dense
// (each wave instruction = 1 KB contiguous) -> DRAM row-sequential streams
// instead of 4 MB-strided 1 KB scatter. Everything else = R4 (best, 53.1us):
// 256 blocks x 1024 thr, 64 KB LDS hist, depth-2 load batch, packed 64-bit
// flush. No launch_bounds VGPR cap (R3/R5 regressions both carried it).
//
// Channel math: int4 index m covers flat ints [4m,4m+4) -> channels
// (m&15)*4 .. +3. Segment start seg0 = b*62500 (62500%16==4) and all loop
// steps are multiples of 1024 -> (m&15) = ((seg0+tid)&15) per-thread const.

#define NCH   64
#define NBINS 256
#define HIST_SIZE (NCH * NBINS)   // 16384 ints = 64 KB LDS
#define NQWORDS   (HIST_SIZE / 2) // 8192 packed pairs
#define THREADS 1024
#define BLOCKS  256               // 1 block/CU

__global__ __launch_bounds__(THREADS) void hist_kernel(
    const int* __restrict__ in, unsigned long long* __restrict__ out,
    long long n4)
{
    __shared__ int hist[HIST_SIZE];
    const int tid = threadIdx.x;

    #pragma unroll
    for (int k = 0; k < HIST_SIZE / THREADS; ++k)
        hist[tid + k * THREADS] = 0;
    __syncthreads();

    const int4* __restrict__ in4 = (const int4*)in;

    // Contiguous per-block segment [seg0, seg_end).
    const long long per_block = (n4 + BLOCKS - 1) / BLOCKS;   // 62500
    const long long seg0 = (long long)blockIdx.x * per_block;
    const long long seg_end = (seg0 + per_block < n4) ? (seg0 + per_block) : n4;
    const int seg_len = (int)(seg_end - seg0);                // <= 62500

    const int c0 = (int)(((seg0 + tid) & 15) << 2);
    int* __restrict__ h = &hist[c0 * NBINS];

    const int4* __restrict__ base = in4 + seg0;

    // Depth-2 main loop: block reads 2x16KB contiguous per iteration.
    const int full2 = seg_len / (2 * THREADS);                // 30
    for (int k = 0; k < full2; ++k) {
        const int j = k * 2 * THREADS + tid;
        int4 a = base[j];
        int4 b = base[j + THREADS];
        atomicAdd(&h[0 * NBINS + a.x], 1); atomicAdd(&h[1 * NBINS + a.y], 1);
        atomicAdd(&h[2 * NBINS + a.z], 1); atomicAdd(&h[3 * NBINS + a.w], 1);
        atomicAdd(&h[0 * NBINS + b.x], 1); atomicAdd(&h[1 * NBINS + b.y], 1);
        atomicAdd(&h[2 * NBINS + b.z], 1); atomicAdd(&h[3 * NBINS + b.w], 1);
    }
    // Tail: up to 2*THREADS-1 int4 remain (steps stay multiples of THREADS).
    int j = full2 * 2 * THREADS + tid;
    if (j < seg_len) {
        int4 a = base[j];
        atomicAdd(&h[0 * NBINS + a.x], 1); atomicAdd(&h[1 * NBINS + a.y], 1);
        atomicAdd(&h[2 * NBINS + a.z], 1); atomicAdd(&h[3 * NBINS + a.w], 1);
    }
    j += THREADS;
    if (j < seg_len) {
        int4 a = base[j];
        atomicAdd(&h[0 * NBINS + a.x], 1); atomicAdd(&h[1 * NBINS + a.y], 1);
        atomicAdd(&h[2 * NBINS + a.z], 1); atomicAdd(&h[3 * NBINS + a.w], 1);
    }
    __syncthreads();

    // Flush block-private histogram as packed 64-bit adds (two bins/atomic).
    // Per-bin totals << 2^32 -> no carry across halves. Rotate start offset
    // per block to spread L2 line contention.
    const unsigned long long* __restrict__ h64 = (const unsigned long long*)hist;
    #pragma unroll
    for (int kk = 0; kk < NQWORDS / THREADS; ++kk) {
        const int jj = (tid + kk * THREADS + blockIdx.x * 32) & (NQWORDS - 1);
        const unsigned long long v = h64[jj];
        if (v) atomicAdd(&out[jj], v);
    }
}

extern "C" void kernel_launch(void* const* d_in, const int* in_sizes, int n_in,
                              void* d_out, int out_size, void* d_ws, size_t ws_size,
                              hipStream_t stream) {
    const int* in = (const int*)d_in[0];
    unsigned long long* out = (unsigned long long*)d_out;
    const long long n = (long long)in_sizes[0];   // 64,000,000 (divisible by 4)
    const long long n4 = n / 4;

    // Replays accumulate via atomics -> must zero the output every launch.
    hipMemsetAsync(d_out, 0, (size_t)out_size * sizeof(int), stream);

    hist_kernel<<<BLOCKS, THREADS, 0, stream>>>(in, out, n4);
}